// Round 4
// baseline (1006.264 us; speedup 1.0000x reference)
//
#include <hip/hip_runtime.h>
#include <hip/hip_bf16.h>

// 3-step Euler residual block via bf16 MFMA implicit-GEMM (R3).
//   t = relu(conv(x,w1)+b1); x += (1/3)*(conv(t,w2)+b2); 3 steps; out = relu(x)
// B=16, C=128, H=W=128. Activations NHWC bf16 in ws (XB = x state, T = t).
//
// R3: 32x32x16 MFMA, wave tile = 128 oc x 64 px (8 acc tiles) -> 6 LDS reads
// per 8 MFMA. Block = 2 output rows x 128 px (4 waves), grid 16*64=1024.
// Staging via global_load_lds width=16 (weights pre-transformed to the exact
// streaming layout). LDS layouts split ci into two 8-elem h-planes so that
// fragment reads are bank-group-sequential (conflict-free).
//
// mfma_f32_32x32x16_bf16: A[m=lane&31][k=(lane>>5)*8+j],
//                         B[k=(lane>>5)*8+j][n=lane&31],
//                         D: col=lane&31, row=(reg&3)+8*(reg>>2)+4*(lane>>5).

#define BATCH 16
#define CH    128
#define HH    128
#define WW    128
#define H_STEP (1.0f/3.0f)

typedef short bf16x8 __attribute__((ext_vector_type(8)));
typedef float f32x16 __attribute__((ext_vector_type(16)));

__device__ __forceinline__ float bf2f(unsigned short u) {
    union { unsigned int i; float f; } c; c.i = ((unsigned int)u) << 16; return c.f;
}
__device__ __forceinline__ unsigned short f2bf(float f) {
    union { float f; unsigned int i; } c; c.f = f;
    unsigned int i = c.i;
    return (unsigned short)((i + 0x7FFFu + ((i >> 16) & 1u)) >> 16);  // RNE
}

__device__ __forceinline__ void gload_lds16(const void* g, void* l) {
    __builtin_amdgcn_global_load_lds(
        (const __attribute__((address_space(1))) unsigned int*)g,
        (__attribute__((address_space(3))) unsigned int*)l, 16, 0, 0);
}

// ---------------- initial transpose: x0 NCHW fp32 -> XB NHWC bf16 --------------
__global__ __launch_bounds__(256)
void transpose_x(const float* __restrict__ x, unsigned short* __restrict__ xb)
{
    __shared__ unsigned short s[128 * 132];   // [ci][x], +4 pad
    const int tid = threadIdx.x;
    const int bz  = blockIdx.x;               // 0..2047 = (b,y)
    const int b = bz >> 7, y = bz & 127;

    #pragma unroll
    for (int it = 0; it < 16; ++it) {
        int idx = it * 256 + tid;             // 0..4095
        int ci = idx >> 5, xq = idx & 31;
        float4 v = *(const float4*)&x[(((size_t)b * CH + ci) * HH + y) * WW + xq * 4];
        uint2 p;
        p.x = (unsigned int)f2bf(v.x) | ((unsigned int)f2bf(v.y) << 16);
        p.y = (unsigned int)f2bf(v.z) | ((unsigned int)f2bf(v.w) << 16);
        *(uint2*)&s[ci * 132 + xq * 4] = p;
    }
    __syncthreads();
    #pragma unroll
    for (int it = 0; it < 8; ++it) {
        int idx = it * 256 + tid;             // 0..2047
        int xx = idx >> 4, cc = idx & 15;
        unsigned short t[8];
        #pragma unroll
        for (int k = 0; k < 8; ++k) t[k] = s[(cc * 8 + k) * 132 + xx];
        uint4 p;
        p.x = (unsigned int)t[0] | ((unsigned int)t[1] << 16);
        p.y = (unsigned int)t[2] | ((unsigned int)t[3] << 16);
        p.z = (unsigned int)t[4] | ((unsigned int)t[5] << 16);
        p.w = (unsigned int)t[6] | ((unsigned int)t[7] << 16);
        *(uint4*)&xb[((size_t)(b * HH + y) * WW + xx) * CH + cc * 8] = p;
    }
}

// ---- weight convert: OIHW fp32 -> WB[c0g(8)][tap(9)][h(2)][oc(128)][8] bf16 ----
// ci = c0g*16 + h*8 + cc. This is exactly the order global_load_lds streams it.
__global__ __launch_bounds__(256)
void convert_w(const float* __restrict__ w, unsigned short* __restrict__ wb)
{
    int idx = blockIdx.x * 256 + threadIdx.x;   // 0..16383 = oc*128+ci
    int oc = idx >> 7, ci = idx & 127;
    int c0g = ci >> 4, h = (ci >> 3) & 1, cc = ci & 7;
    #pragma unroll
    for (int t = 0; t < 9; ++t)
        wb[(((((size_t)c0g * 9 + t) * 2 + h) * 128 + oc) * 8) + cc]
            = f2bf(w[(size_t)idx * 9 + t]);
}

// ------------------------------ conv3x3 MFMA ----------------------------------
// MODE 0: outb = bf16(relu(acc + bias))                   (conv1 -> T)
// MODE 1: outb = bf16(res + h*(acc + bias))               (conv2 -> XB, in place)
// MODE 2: outf = relu(res + h*(acc + bias)) fp32 NCHW     (final conv2 -> d_out)
template<int MODE>
__global__ __launch_bounds__(256, 2)
void conv_mfma(const unsigned short* __restrict__ in,   // NHWC bf16
               const unsigned short* __restrict__ wb,   // [8][9][2][128][8] bf16
               const float* __restrict__ bias,
               const unsigned short* resb,              // NHWC bf16 (may alias outb)
               unsigned short* outb,                    // NHWC bf16
               float* __restrict__ outf)                // NCHW fp32
{
    // s_w[tap][h][oc][8]: A-read lane(m=lane&31) -> addr m*16B: groups 0..7 ok
    __shared__ unsigned short s_w[9 * 2 * 128 * 8];     // 36,864 B
    // s_in[h][rs(4)][slot(130)][8]: B-read lane(n) -> addr n*16B: groups 0..7 ok
    __shared__ unsigned short s_in[2 * 4 * 130 * 8];    // 16,640 B

    const int tid  = threadIdx.x;
    const int bz   = blockIdx.x;              // 0..1023
    const int b    = bz >> 6;
    const int y0   = (bz & 63) * 2;           // band rows y0, y0+1

    const int lane = tid & 63;
    const int wid  = tid >> 6;
    const int rw   = wid >> 1;                // wave's output row (0/1)
    const int xw   = (wid & 1) * 64;          // wave's x-half base
    const int n    = lane & 31;
    const int h    = lane >> 5;

    // ---- one-time zero: x-halo slots (0,129) and the (single) invalid row ----
    if (tid < 16) {
        int hh2 = tid >> 3, rrs = (tid >> 1) & 3, sl = (tid & 1) ? 129 : 0;
        uint4 z = {0u, 0u, 0u, 0u};
        *(uint4*)&s_in[((hh2 * 4 + rrs) * 130 + sl) * 8] = z;
    }
    {
        int bad_rs = (y0 == 0) ? 0 : ((y0 == 126) ? 3 : -1);
        if (bad_rs >= 0) {
            for (int i2 = tid; i2 < 2 * 130; i2 += 256) {
                int hh2 = i2 / 130, sl = i2 % 130;
                uint4 z = {0u, 0u, 0u, 0u};
                *(uint4*)&s_in[((hh2 * 4 + bad_rs) * 130 + sl) * 8] = z;
            }
        }
    }

    f32x16 acc[4][2];
    #pragma unroll
    for (int i = 0; i < 4; ++i)
        #pragma unroll
        for (int j = 0; j < 2; ++j) acc[i][j] = (f32x16)0.0f;

    // wave wid stages input row rs = wid (gy = y0 + wid - 1)
    const int  my_gy    = y0 + wid - 1;
    const bool my_valid = (my_gy >= 0) && (my_gy < HH);
    const char* inrow   = (const char*)(in + ((size_t)(b * HH + my_gy) * WW) * CH);
    const char* wbc     = (const char*)wb;

    for (int c0g = 0; c0g < 8; ++c0g) {
        __syncthreads();                       // prior chunk's readers done
        // ---- stage weights: wave wid streams its 9216B contiguous slice ----
        {
            const char* gsrc = wbc + c0g * 36864 + wid * 9216;
            char*       ldst = (char*)s_w + wid * 9216;
            #pragma unroll
            for (int it = 0; it < 9; ++it)
                gload_lds16(gsrc + it * 1024 + lane * 16,
                            ldst + it * 1024 + lane * 16);
        }
        // ---- stage input row rs = wid, ci chunk c0g (2 h-planes x 2 halves) --
        if (my_valid) {
            #pragma unroll
            for (int hh2 = 0; hh2 < 2; ++hh2)
                #pragma unroll
                for (int half = 0; half < 2; ++half) {
                    int x = half * 64 + lane;
                    gload_lds16(inrow + (size_t)x * 256 + c0g * 32 + hh2 * 16,
                                (char*)&s_in[((hh2 * 4 + wid) * 130 + 1 + half * 64) * 8]
                                    + lane * 16);
                }
        }
        __syncthreads();                       // staging visible (vmcnt drained)

        // ---- 9 taps x (4 A-frags, 2 B-frags, 8 mfma) ----
        #pragma unroll
        for (int ky = 0; ky < 3; ++ky) {
            const int rs = rw + ky;
            #pragma unroll
            for (int kx = 0; kx < 3; ++kx) {
                const int tap = ky * 3 + kx;
                bf16x8 af[4], bfr[2];
                #pragma unroll
                for (int i = 0; i < 4; ++i)
                    af[i] = *(const bf16x8*)&s_w[((tap * 2 + h) * 128 + i * 32 + n) * 8];
                #pragma unroll
                for (int j = 0; j < 2; ++j)
                    bfr[j] = *(const bf16x8*)&s_in[((h * 4 + rs) * 130 + xw + j * 32 + n + kx) * 8];
                #pragma unroll
                for (int i = 0; i < 4; ++i)
                    #pragma unroll
                    for (int j = 0; j < 2; ++j)
                        acc[i][j] = __builtin_amdgcn_mfma_f32_32x32x16_bf16(
                            af[i], bfr[j], acc[i][j], 0, 0, 0);
            }
        }
    }

    // ------------------------------ epilogue ---------------------------------
    const int y_r = y0 + rw;
    if (MODE == 0 || MODE == 1) {
        #pragma unroll
        for (int j = 0; j < 2; ++j) {
            const int x = xw + j * 32 + n;
            const size_t pbase = ((size_t)(b * HH + y_r) * WW + x) * CH;
            #pragma unroll
            for (int i = 0; i < 4; ++i) {
                #pragma unroll
                for (int a = 0; a < 4; ++a) {
                    const int oc0 = i * 32 + a * 8 + h * 4;   // 4 consecutive oc
                    float4 bv = *(const float4*)&bias[oc0];
                    float v0 = acc[i][j][a * 4 + 0] + bv.x;
                    float v1 = acc[i][j][a * 4 + 1] + bv.y;
                    float v2 = acc[i][j][a * 4 + 2] + bv.z;
                    float v3 = acc[i][j][a * 4 + 3] + bv.w;
                    if (MODE == 0) {
                        v0 = fmaxf(v0, 0.f); v1 = fmaxf(v1, 0.f);
                        v2 = fmaxf(v2, 0.f); v3 = fmaxf(v3, 0.f);
                    } else {
                        uint2 rr = *(const uint2*)&resb[pbase + oc0];
                        v0 = bf2f((unsigned short)(rr.x & 0xffff)) + H_STEP * v0;
                        v1 = bf2f((unsigned short)(rr.x >> 16))    + H_STEP * v1;
                        v2 = bf2f((unsigned short)(rr.y & 0xffff)) + H_STEP * v2;
                        v3 = bf2f((unsigned short)(rr.y >> 16))    + H_STEP * v3;
                    }
                    uint2 po;
                    po.x = (unsigned int)f2bf(v0) | ((unsigned int)f2bf(v1) << 16);
                    po.y = (unsigned int)f2bf(v2) | ((unsigned int)f2bf(v3) << 16);
                    *(uint2*)&outb[pbase + oc0] = po;
                }
            }
        }
    } else {
        // final: fp32 NCHW + relu; residual bf16 NHWC
        #pragma unroll
        for (int i = 0; i < 4; ++i) {
            #pragma unroll
            for (int a = 0; a < 4; ++a) {
                #pragma unroll
                for (int r = 0; r < 4; ++r) {
                    const int oc = i * 32 + a * 8 + h * 4 + r;
                    const float bv = bias[oc];
                    const size_t orow = ((size_t)(b * CH + oc) * HH + y_r) * WW;
                    #pragma unroll
                    for (int j = 0; j < 2; ++j) {
                        const int x = xw + j * 32 + n;
                        float v = acc[i][j][a * 4 + r] + bv;
                        v = bf2f(resb[((size_t)(b * HH + y_r) * WW + x) * CH + oc])
                            + H_STEP * v;
                        outf[orow + x] = fmaxf(v, 0.f);
                    }
                }
            }
        }
    }
}

// ------------------------------------------------------------------------------
extern "C" void kernel_launch(void* const* d_in, const int* in_sizes, int n_in,
                              void* d_out, int out_size, void* d_ws, size_t ws_size,
                              hipStream_t stream) {
    const float* x0 = (const float*)d_in[0];
    const float* w1 = (const float*)d_in[1];
    const float* b1 = (const float*)d_in[2];
    const float* w2 = (const float*)d_in[3];
    const float* b2 = (const float*)d_in[4];

    const size_t NELEM = (size_t)BATCH * CH * HH * WW;       // 33,554,432
    unsigned short* XB = (unsigned short*)d_ws;              // x state, NHWC bf16
    unsigned short* T  = XB + NELEM;                         // t,       NHWC bf16

    unsigned short* WB1;
    if (ws_size >= NELEM * 4 + 2 * 294912)
        WB1 = T + NELEM;
    else
        WB1 = (unsigned short*)d_in[0];                      // dead after transpose
    unsigned short* WB2 = WB1 + 9 * 16384;

    dim3 block(256);
    dim3 gridT(BATCH * HH);          // 2048 (transpose: one block per row)
    dim3 gridC(BATCH * (HH / 2));    // 1024 (conv: one block per 2-row band)

    transpose_x<<<gridT, block, 0, stream>>>(x0, XB);        // reads x0 first
    convert_w<<<dim3(64), block, 0, stream>>>(w1, WB1);      // then x0 clobber ok
    convert_w<<<dim3(64), block, 0, stream>>>(w2, WB2);

    // step 1
    conv_mfma<0><<<gridC, block, 0, stream>>>(XB, WB1, b1, nullptr, T, nullptr);
    conv_mfma<1><<<gridC, block, 0, stream>>>(T, WB2, b2, XB, XB, nullptr);
    // step 2
    conv_mfma<0><<<gridC, block, 0, stream>>>(XB, WB1, b1, nullptr, T, nullptr);
    conv_mfma<1><<<gridC, block, 0, stream>>>(T, WB2, b2, XB, XB, nullptr);
    // step 3 (final relu, fp32 NCHW out)
    conv_mfma<0><<<gridC, block, 0, stream>>>(XB, WB1, b1, nullptr, T, nullptr);
    conv_mfma<2><<<gridC, block, 0, stream>>>(T, WB2, b2, XB, nullptr, (float*)d_out);
}

// Round 5
// 999.585 us; speedup vs baseline: 1.0067x; 1.0067x over previous
//
#include <hip/hip_runtime.h>
#include <hip/hip_bf16.h>

// 3-step Euler residual block via bf16 MFMA implicit-GEMM (R4).
//   t = relu(conv(x,w1)+b1); x += (1/3)*(conv(t,w2)+b2); 3 steps; out = relu(x)
// B=16, C=128, H=W=128. Activations NHWC bf16 in ws (XB = x state, T = t).
//
// R4: R3's tiling (32x32x16 MFMA, wave = 128 oc x 64 px, block = 2 rows,
// conflict-free split-h LDS layouts) but staging back on the VGPR path
// (plain uint4 loads + ds_write). R3's global_load_lds weight stream missed
// L2 (FETCH 134->365 MB/conv) and its per-chunk vmcnt(0) drain serialized
// HBM latency against only 576 cyc of MFMA. All 13 loads per chunk issue
// before the first ds_write so the waits pipeline.
//
// mfma_f32_32x32x16_bf16: A[m=lane&31][k=(lane>>5)*8+j],
//                         B[k=(lane>>5)*8+j][n=lane&31],
//                         D: col=lane&31, row=(reg&3)+8*(reg>>2)+4*(lane>>5).

#define BATCH 16
#define CH    128
#define HH    128
#define WW    128
#define H_STEP (1.0f/3.0f)

typedef short bf16x8 __attribute__((ext_vector_type(8)));
typedef float f32x16 __attribute__((ext_vector_type(16)));

__device__ __forceinline__ float bf2f(unsigned short u) {
    union { unsigned int i; float f; } c; c.i = ((unsigned int)u) << 16; return c.f;
}
__device__ __forceinline__ unsigned short f2bf(float f) {
    union { float f; unsigned int i; } c; c.f = f;
    unsigned int i = c.i;
    return (unsigned short)((i + 0x7FFFu + ((i >> 16) & 1u)) >> 16);  // RNE
}

// ---------------- initial transpose: x0 NCHW fp32 -> XB NHWC bf16 --------------
__global__ __launch_bounds__(256)
void transpose_x(const float* __restrict__ x, unsigned short* __restrict__ xb)
{
    __shared__ unsigned short s[128 * 132];   // [ci][x], +4 pad
    const int tid = threadIdx.x;
    const int bz  = blockIdx.x;               // 0..2047 = (b,y)
    const int b = bz >> 7, y = bz & 127;

    #pragma unroll
    for (int it = 0; it < 16; ++it) {
        int idx = it * 256 + tid;             // 0..4095
        int ci = idx >> 5, xq = idx & 31;
        float4 v = *(const float4*)&x[(((size_t)b * CH + ci) * HH + y) * WW + xq * 4];
        uint2 p;
        p.x = (unsigned int)f2bf(v.x) | ((unsigned int)f2bf(v.y) << 16);
        p.y = (unsigned int)f2bf(v.z) | ((unsigned int)f2bf(v.w) << 16);
        *(uint2*)&s[ci * 132 + xq * 4] = p;
    }
    __syncthreads();
    #pragma unroll
    for (int it = 0; it < 8; ++it) {
        int idx = it * 256 + tid;             // 0..2047
        int xx = idx >> 4, cc = idx & 15;
        unsigned short t[8];
        #pragma unroll
        for (int k = 0; k < 8; ++k) t[k] = s[(cc * 8 + k) * 132 + xx];
        uint4 p;
        p.x = (unsigned int)t[0] | ((unsigned int)t[1] << 16);
        p.y = (unsigned int)t[2] | ((unsigned int)t[3] << 16);
        p.z = (unsigned int)t[4] | ((unsigned int)t[5] << 16);
        p.w = (unsigned int)t[6] | ((unsigned int)t[7] << 16);
        *(uint4*)&xb[((size_t)(b * HH + y) * WW + xx) * CH + cc * 8] = p;
    }
}

// ---- weight convert: OIHW fp32 -> WB[c0g(8)][tap(9)][h(2)][oc(128)][8] bf16 ----
// ci = c0g*16 + h*8 + cc. Linear in exactly the order conv streams it.
__global__ __launch_bounds__(256)
void convert_w(const float* __restrict__ w, unsigned short* __restrict__ wb)
{
    int idx = blockIdx.x * 256 + threadIdx.x;   // 0..16383 = oc*128+ci
    int oc = idx >> 7, ci = idx & 127;
    int c0g = ci >> 4, h = (ci >> 3) & 1, cc = ci & 7;
    #pragma unroll
    for (int t = 0; t < 9; ++t)
        wb[(((((size_t)c0g * 9 + t) * 2 + h) * 128 + oc) * 8) + cc]
            = f2bf(w[(size_t)idx * 9 + t]);
}

// ------------------------------ conv3x3 MFMA ----------------------------------
// MODE 0: outb = bf16(relu(acc + bias))                   (conv1 -> T)
// MODE 1: outb = bf16(res + h*(acc + bias))               (conv2 -> XB, in place)
// MODE 2: outf = relu(res + h*(acc + bias)) fp32 NCHW     (final conv2 -> d_out)
template<int MODE>
__global__ __launch_bounds__(256, 2)
void conv_mfma(const unsigned short* __restrict__ in,   // NHWC bf16
               const unsigned short* __restrict__ wb,   // [8][9][2][128][8] bf16
               const float* __restrict__ bias,
               const unsigned short* resb,              // NHWC bf16 (may alias outb)
               unsigned short* outb,                    // NHWC bf16
               float* __restrict__ outf)                // NCHW fp32
{
    // s_w[tap][h][oc][8]: A-read lane(m=lane&31) -> 16B groups 0..7, conflict-free
    __shared__ __align__(16) unsigned short s_w[9 * 2 * 128 * 8];   // 36,864 B
    // s_in[h][rs(4)][slot(130)][8]: B-read lane(n) -> 16B groups, conflict-free
    __shared__ __align__(16) unsigned short s_in[2 * 4 * 130 * 8];  // 16,640 B

    const int tid  = threadIdx.x;
    const int bz   = blockIdx.x;              // 0..1023
    const int b    = bz >> 6;
    const int y0   = (bz & 63) * 2;           // band rows y0, y0+1

    const int lane = tid & 63;
    const int wid  = tid >> 6;
    const int rw   = wid >> 1;                // wave's output row (0/1)
    const int xw   = (wid & 1) * 64;          // wave's x-half base
    const int n    = lane & 31;
    const int h    = lane >> 5;

    // ---- one-time zero: x-halo slots (0,129) and the (single) invalid row ----
    if (tid < 16) {
        int hh2 = tid >> 3, rrs = (tid >> 1) & 3, sl = (tid & 1) ? 129 : 0;
        uint4 z = {0u, 0u, 0u, 0u};
        *(uint4*)&s_in[((hh2 * 4 + rrs) * 130 + sl) * 8] = z;
    }
    {
        int bad_rs = (y0 == 0) ? 0 : ((y0 == 126) ? 3 : -1);
        if (bad_rs >= 0) {
            for (int i2 = tid; i2 < 2 * 130; i2 += 256) {
                int hh2 = i2 / 130, sl = i2 % 130;
                uint4 z = {0u, 0u, 0u, 0u};
                *(uint4*)&s_in[((hh2 * 4 + bad_rs) * 130 + sl) * 8] = z;
            }
        }
    }

    f32x16 acc[4][2];
    #pragma unroll
    for (int i = 0; i < 4; ++i)
        #pragma unroll
        for (int j = 0; j < 2; ++j) acc[i][j] = (f32x16)0.0f;

    // wave wid stages input row rs = wid (gy = y0 + wid - 1)
    const int  my_gy    = y0 + wid - 1;
    const bool my_valid = (my_gy >= 0) && (my_gy < HH);
    const char* inrow   = (const char*)(in + ((size_t)(b * HH + my_gy) * WW) * CH);
    const char* wbc     = (const char*)wb;

    for (int c0g = 0; c0g < 8; ++c0g) {
        __syncthreads();                       // prior chunk's readers done

        // ---- issue ALL global loads for this chunk first (13 uint4/thread) ---
        uint4 wtmp[9];
        {
            const uint4* gsrc = (const uint4*)(wbc + c0g * 36864);
            #pragma unroll
            for (int it = 0; it < 9; ++it)
                wtmp[it] = gsrc[it * 256 + tid];
        }
        uint4 itmp[4];
        if (my_valid) {
            #pragma unroll
            for (int hh2 = 0; hh2 < 2; ++hh2)
                #pragma unroll
                for (int half = 0; half < 2; ++half) {
                    int x = half * 64 + lane;
                    itmp[hh2 * 2 + half] = *(const uint4*)
                        (inrow + (size_t)x * 256 + c0g * 32 + hh2 * 16);
                }
        }
        // ---- then ds_write (vmcnt retires oldest-first -> pipelined) --------
        #pragma unroll
        for (int it = 0; it < 9; ++it)
            *(uint4*)((char*)s_w + (it * 256 + tid) * 16) = wtmp[it];
        if (my_valid) {
            #pragma unroll
            for (int hh2 = 0; hh2 < 2; ++hh2)
                #pragma unroll
                for (int half = 0; half < 2; ++half)
                    *(uint4*)((char*)&s_in[((hh2 * 4 + wid) * 130 + 1 + half * 64) * 8]
                              + lane * 16) = itmp[hh2 * 2 + half];
        }
        __syncthreads();                       // staging visible

        // ---- 9 taps x (4 A-frags, 2 B-frags, 8 mfma) ----
        #pragma unroll
        for (int ky = 0; ky < 3; ++ky) {
            const int rs = rw + ky;
            #pragma unroll
            for (int kx = 0; kx < 3; ++kx) {
                const int tap = ky * 3 + kx;
                bf16x8 af[4], bfr[2];
                #pragma unroll
                for (int i = 0; i < 4; ++i)
                    af[i] = *(const bf16x8*)&s_w[((tap * 2 + h) * 128 + i * 32 + n) * 8];
                #pragma unroll
                for (int j = 0; j < 2; ++j)
                    bfr[j] = *(const bf16x8*)&s_in[((h * 4 + rs) * 130 + xw + j * 32 + n + kx) * 8];
                #pragma unroll
                for (int i = 0; i < 4; ++i)
                    #pragma unroll
                    for (int j = 0; j < 2; ++j)
                        acc[i][j] = __builtin_amdgcn_mfma_f32_32x32x16_bf16(
                            af[i], bfr[j], acc[i][j], 0, 0, 0);
            }
        }
    }

    // ------------------------------ epilogue ---------------------------------
    const int y_r = y0 + rw;
    if (MODE == 0 || MODE == 1) {
        #pragma unroll
        for (int j = 0; j < 2; ++j) {
            const int x = xw + j * 32 + n;
            const size_t pbase = ((size_t)(b * HH + y_r) * WW + x) * CH;
            #pragma unroll
            for (int i = 0; i < 4; ++i) {
                #pragma unroll
                for (int a = 0; a < 4; ++a) {
                    const int oc0 = i * 32 + a * 8 + h * 4;   // 4 consecutive oc
                    float4 bv = *(const float4*)&bias[oc0];
                    float v0 = acc[i][j][a * 4 + 0] + bv.x;
                    float v1 = acc[i][j][a * 4 + 1] + bv.y;
                    float v2 = acc[i][j][a * 4 + 2] + bv.z;
                    float v3 = acc[i][j][a * 4 + 3] + bv.w;
                    if (MODE == 0) {
                        v0 = fmaxf(v0, 0.f); v1 = fmaxf(v1, 0.f);
                        v2 = fmaxf(v2, 0.f); v3 = fmaxf(v3, 0.f);
                    } else {
                        uint2 rr = *(const uint2*)&resb[pbase + oc0];
                        v0 = bf2f((unsigned short)(rr.x & 0xffff)) + H_STEP * v0;
                        v1 = bf2f((unsigned short)(rr.x >> 16))    + H_STEP * v1;
                        v2 = bf2f((unsigned short)(rr.y & 0xffff)) + H_STEP * v2;
                        v3 = bf2f((unsigned short)(rr.y >> 16))    + H_STEP * v3;
                    }
                    uint2 po;
                    po.x = (unsigned int)f2bf(v0) | ((unsigned int)f2bf(v1) << 16);
                    po.y = (unsigned int)f2bf(v2) | ((unsigned int)f2bf(v3) << 16);
                    *(uint2*)&outb[pbase + oc0] = po;
                }
            }
        }
    } else {
        // final: fp32 NCHW + relu; residual bf16 NHWC
        #pragma unroll
        for (int i = 0; i < 4; ++i) {
            #pragma unroll
            for (int a = 0; a < 4; ++a) {
                #pragma unroll
                for (int r = 0; r < 4; ++r) {
                    const int oc = i * 32 + a * 8 + h * 4 + r;
                    const float bv = bias[oc];
                    const size_t orow = ((size_t)(b * CH + oc) * HH + y_r) * WW;
                    #pragma unroll
                    for (int j = 0; j < 2; ++j) {
                        const int x = xw + j * 32 + n;
                        float v = acc[i][j][a * 4 + r] + bv;
                        v = bf2f(resb[((size_t)(b * HH + y_r) * WW + x) * CH + oc])
                            + H_STEP * v;
                        outf[orow + x] = fmaxf(v, 0.f);
                    }
                }
            }
        }
    }
}

// ------------------------------------------------------------------------------
extern "C" void kernel_launch(void* const* d_in, const int* in_sizes, int n_in,
                              void* d_out, int out_size, void* d_ws, size_t ws_size,
                              hipStream_t stream) {
    const float* x0 = (const float*)d_in[0];
    const float* w1 = (const float*)d_in[1];
    const float* b1 = (const float*)d_in[2];
    const float* w2 = (const float*)d_in[3];
    const float* b2 = (const float*)d_in[4];

    const size_t NELEM = (size_t)BATCH * CH * HH * WW;       // 33,554,432
    unsigned short* XB = (unsigned short*)d_ws;              // x state, NHWC bf16
    unsigned short* T  = XB + NELEM;                         // t,       NHWC bf16

    unsigned short* WB1;
    if (ws_size >= NELEM * 4 + 2 * 294912)
        WB1 = T + NELEM;
    else
        WB1 = (unsigned short*)d_in[0];                      // dead after transpose
    unsigned short* WB2 = WB1 + 9 * 16384;

    dim3 block(256);
    dim3 gridT(BATCH * HH);          // 2048 (transpose: one block per row)
    dim3 gridC(BATCH * (HH / 2));    // 1024 (conv: one block per 2-row band)

    transpose_x<<<gridT, block, 0, stream>>>(x0, XB);        // reads x0 first
    convert_w<<<dim3(64), block, 0, stream>>>(w1, WB1);      // then x0 clobber ok
    convert_w<<<dim3(64), block, 0, stream>>>(w2, WB2);

    // step 1
    conv_mfma<0><<<gridC, block, 0, stream>>>(XB, WB1, b1, nullptr, T, nullptr);
    conv_mfma<1><<<gridC, block, 0, stream>>>(T, WB2, b2, XB, XB, nullptr);
    // step 2
    conv_mfma<0><<<gridC, block, 0, stream>>>(XB, WB1, b1, nullptr, T, nullptr);
    conv_mfma<1><<<gridC, block, 0, stream>>>(T, WB2, b2, XB, XB, nullptr);
    // step 3 (final relu, fp32 NCHW out)
    conv_mfma<0><<<gridC, block, 0, stream>>>(XB, WB1, b1, nullptr, T, nullptr);
    conv_mfma<2><<<gridC, block, 0, stream>>>(T, WB2, b2, XB, nullptr, (float*)d_out);
}